// Round 3
// baseline (2041.708 us; speedup 1.0000x reference)
//
#include <hip/hip_runtime.h>
#include <hip/hip_bf16.h>
#include <stdint.h>

// CachedOPTAttention: B=4, T=1024, D=2048, H=32, HD=64, causal, idx=0.
// Buffers are FP32 (per reference dtypes). Error budget is bf16-class
// (threshold 0.10125 = 8*2^-8*max|ref|), so GEMMs convert fp32->bf16 at LDS
// staging and use mfma_f32_16x16x32_bf16; attention is pure fp32 VALU.
// Output: out (8,388,608 f32) ++ new_cache (16,777,216 f32).
// cache_update_index==0, update len == max_len -> cache fully overwritten;
// K/V GEMMs write straight into d_out's cache region.
//
// Buffer plan:
//   Q GEMM    : x @ Wq -> d_out[0 : 8M)        (out region, dead until O GEMM)
//   K,V GEMMs : x @ Wk/Wv -> d_out[8M : 24M)   (new_cache region — final output)
//   attention : q (out region) x cache -> ctx in d_ws (33.5 MB)
//   O GEMM    : ctx @ Wo -> d_out[0 : 8M)

typedef __hip_bfloat16 bf16;
typedef short s16x8 __attribute__((ext_vector_type(8)));
typedef float f32x4 __attribute__((ext_vector_type(4)));

#define T_SEQ   1024
#define D_MODEL 2048

__device__ inline unsigned short f2b(float f) {
    bf16 h = __float2bfloat16(f);
    return *(unsigned short*)&h;
}

// ---------------------------------------------------------------------------
// GEMM: C[M=4096, N=2048] = A[M, K=2048] @ W[K, N] + bias[N]   (all fp32)
// 64x64 tile / 256-thread block, BK=32, bf16 MFMA with fp32->bf16 staging.
// mode 0: out[m*2048 + n]
// mode 1: cache scatter: b=m>>10, t=m&1023 ->
//         out[((b*2+slot)*1024 + ((t+idx)&1023))*2048 + n]
// ---------------------------------------------------------------------------
__global__ __launch_bounds__(256)
void gemm64_kernel(const float* __restrict__ A, const float* __restrict__ W,
                   const float* __restrict__ bias, float* __restrict__ out,
                   int mode, int slot, const int* __restrict__ idxp)
{
    __shared__ __align__(16) unsigned short As[64 * 32];
    __shared__ __align__(16) unsigned short Bs[64 * 32];  // W^T tile: Bs[n][k]

    const int tid  = threadIdx.x;
    const int m0   = blockIdx.y * 64;
    const int n0   = blockIdx.x * 64;
    const int wave = tid >> 6;
    const int lane = tid & 63;
    const int quad = lane >> 4;
    const int l15  = lane & 15;

    const int ar = tid >> 2;        // A tile row 0..63
    const int ac = (tid & 3) * 8;   // A tile col {0,8,16,24}
    const int wk = tid >> 3;        // W tile k 0..31
    const int wc = (tid & 7) * 8;   // W tile n {0..56}

    f32x4 acc[4];
    #pragma unroll
    for (int t = 0; t < 4; ++t) acc[t] = f32x4{0.f, 0.f, 0.f, 0.f};

    const float4* ag = (const float4*)(A + (size_t)(m0 + ar) * D_MODEL + ac);
    const float4* wg = (const float4*)(W + (size_t)wk * D_MODEL + n0 + wc);

    for (int k0 = 0; k0 < D_MODEL; k0 += 32) {
        // stage A tile (64x32): 8 fp32 -> 8 bf16 per thread, one b128 store
        float4 a0 = ag[(k0 >> 2) + 0];      // advance k0 floats
        float4 a1 = ag[(k0 >> 2) + 1];
        union { uint4 u; unsigned short s[8]; } ap;
        ap.s[0] = f2b(a0.x); ap.s[1] = f2b(a0.y); ap.s[2] = f2b(a0.z); ap.s[3] = f2b(a0.w);
        ap.s[4] = f2b(a1.x); ap.s[5] = f2b(a1.y); ap.s[6] = f2b(a1.z); ap.s[7] = f2b(a1.w);
        *(uint4*)(As + ar * 32 + ac) = ap.u;

        // stage W tile (32x64) transposed into Bs[n][k]
        float4 w0 = wg[((size_t)k0 << 9) + 0]; // advance k0 rows = k0*512 float4
        float4 w1 = wg[((size_t)k0 << 9) + 1];
        float wv[8] = {w0.x, w0.y, w0.z, w0.w, w1.x, w1.y, w1.z, w1.w};
        #pragma unroll
        for (int j = 0; j < 8; ++j) Bs[(wc + j) * 32 + wk] = f2b(wv[j]);
        __syncthreads();

        // A frag: A[m = wave*16 + l15][k = quad*8 + j]
        s16x8 af = *(const s16x8*)(As + (wave * 16 + l15) * 32 + quad * 8);
        #pragma unroll
        for (int t = 0; t < 4; ++t) {
            // B frag: W[k = quad*8 + j][n = t*16 + l15]
            s16x8 bfr = *(const s16x8*)(Bs + (t * 16 + l15) * 32 + quad * 8);
            acc[t] = __builtin_amdgcn_mfma_f32_16x16x32_bf16(af, bfr, acc[t], 0, 0, 0);
        }
        __syncthreads();
    }

    const int idx = (mode == 1) ? idxp[0] : 0;
    #pragma unroll
    for (int t = 0; t < 4; ++t) {
        const int col = n0 + t * 16 + l15;
        const float bv = bias[col];
        #pragma unroll
        for (int r = 0; r < 4; ++r) {
            const int m = m0 + wave * 16 + quad * 4 + r;  // C/D: row=quad*4+reg
            const float v = acc[t][r] + bv;
            size_t off;
            if (mode == 0) {
                off = (size_t)m * D_MODEL + col;
            } else {
                const int b  = m >> 10;
                const int tt = ((m & 1023) + idx) & 1023;
                off = ((size_t)(b * 2 + slot) * T_SEQ + tt) * D_MODEL + col;
            }
            out[off] = v;
        }
    }
}

// ---------------------------------------------------------------------------
// Flash-style causal attention, pure fp32. One thread per query row (per
// head); 64-key x 64-dim K/V tiles staged in LDS; inner reads wave-uniform.
// Online softmax in 8-key groups. Mask arithmetic: score=-1e30 if key>query.
// q, ctx: (B*T, 2048) f32; cache: (B, 2, T, 2048) f32.
// ---------------------------------------------------------------------------
__global__ __launch_bounds__(256)
void attn_kernel(const float* __restrict__ q, const float* __restrict__ cache,
                 float* __restrict__ ctx)
{
    __shared__ float Ks[64 * 64];
    __shared__ float Vs[64 * 64];

    const int tid = threadIdx.x;
    const int qi  = blockIdx.x * 256 + tid;
    const int b   = blockIdx.y >> 5;   // H=32
    const int h   = blockIdx.y & 31;

    const float* kbase = cache + ((size_t)(b * 2 + 0) * T_SEQ) * D_MODEL + h * 64;
    const float* vbase = cache + ((size_t)(b * 2 + 1) * T_SEQ) * D_MODEL + h * 64;

    // q row (64 f32), pre-scaled by 1/sqrt(64)
    float qr[64];
    {
        const float4* qv = (const float4*)(q + (size_t)(b * T_SEQ + qi) * D_MODEL + h * 64);
        #pragma unroll
        for (int i = 0; i < 16; ++i) {
            float4 u = qv[i];
            qr[i * 4 + 0] = u.x * 0.125f;
            qr[i * 4 + 1] = u.y * 0.125f;
            qr[i * 4 + 2] = u.z * 0.125f;
            qr[i * 4 + 3] = u.w * 0.125f;
        }
    }

    float m_run = -1e30f, l_run = 0.f;
    float accd[64];
    #pragma unroll
    for (int d = 0; d < 64; ++d) accd[d] = 0.f;

    const int r = tid >> 2;          // staging: key row in tile
    const int c = (tid & 3) * 16;    // staging: dim offset {0,16,32,48}
    const int ntiles = blockIdx.x * 4 + 4;   // causal bound for this block

    for (int kt = 0; kt < ntiles; ++kt) {
        const float4* kg = (const float4*)(kbase + (size_t)(kt * 64 + r) * D_MODEL + c);
        const float4* vg = (const float4*)(vbase + (size_t)(kt * 64 + r) * D_MODEL + c);
        float4* ks = (float4*)(Ks + r * 64 + c);
        float4* vs = (float4*)(Vs + r * 64 + c);
        #pragma unroll
        for (int j = 0; j < 4; ++j) ks[j] = kg[j];
        #pragma unroll
        for (int j = 0; j < 4; ++j) vs[j] = vg[j];
        __syncthreads();

        #pragma unroll 1
        for (int g = 0; g < 8; ++g) {
            const int key0 = kt * 64 + g * 8;
            float s[8];
            #pragma unroll
            for (int kk = 0; kk < 8; ++kk) {
                const float* kr = Ks + (g * 8 + kk) * 64;
                float a0 = 0.f, a1 = 0.f, a2 = 0.f, a3 = 0.f;
                #pragma unroll
                for (int d4 = 0; d4 < 16; ++d4) {
                    a0 += qr[d4 * 4 + 0] * kr[d4 * 4 + 0];
                    a1 += qr[d4 * 4 + 1] * kr[d4 * 4 + 1];
                    a2 += qr[d4 * 4 + 2] * kr[d4 * 4 + 2];
                    a3 += qr[d4 * 4 + 3] * kr[d4 * 4 + 3];
                }
                const float sc = (a0 + a1) + (a2 + a3);
                s[kk] = (key0 + kk <= qi) ? sc : -1e30f;
            }
            float tmax = s[0];
            #pragma unroll
            for (int kk = 1; kk < 8; ++kk) tmax = fmaxf(tmax, s[kk]);
            const float mnew  = fmaxf(m_run, tmax);
            const float alpha = __expf(m_run - mnew);
            m_run = mnew;
            l_run *= alpha;
            #pragma unroll
            for (int d = 0; d < 64; ++d) accd[d] *= alpha;
            #pragma unroll
            for (int kk = 0; kk < 8; ++kk) {
                const float p = __expf(s[kk] - m_run);
                l_run += p;
                const float* vr = Vs + (g * 8 + kk) * 64;
                #pragma unroll
                for (int d = 0; d < 64; ++d) accd[d] += p * vr[d];
            }
        }
        __syncthreads();
    }

    const float inv = 1.0f / l_run;
    float4* ov = (float4*)(ctx + (size_t)(b * T_SEQ + qi) * D_MODEL + h * 64);
    #pragma unroll
    for (int i = 0; i < 16; ++i) {
        ov[i] = make_float4(accd[i * 4 + 0] * inv, accd[i * 4 + 1] * inv,
                            accd[i * 4 + 2] * inv, accd[i * 4 + 3] * inv);
    }
}

// ---------------------------------------------------------------------------
extern "C" void kernel_launch(void* const* d_in, const int* in_sizes, int n_in,
                              void* d_out, int out_size, void* d_ws, size_t ws_size,
                              hipStream_t stream)
{
    const float* x    = (const float*)d_in[0];
    // d_in[1] = attention_mask (tril 0 / -1e9): computed arithmetically.
    // d_in[2] = cache input: fully overwritten (idx=0, update len == max_len).
    const int*   idxp = (const int*)d_in[3];
    const float* Wq   = (const float*)d_in[4];
    const float* bq   = (const float*)d_in[5];
    const float* Wk   = (const float*)d_in[6];
    const float* bk   = (const float*)d_in[7];
    const float* Wv   = (const float*)d_in[8];
    const float* bv   = (const float*)d_in[9];
    const float* Wo   = (const float*)d_in[10];
    const float* bo   = (const float*)d_in[11];

    float* out      = (float*)d_out;
    float* cacheOut = out + (size_t)4 * T_SEQ * D_MODEL;  // new_cache region
    float* wsctx    = (float*)d_ws;                        // ctx scratch (33.5 MB)

    const dim3 gg(32, 64), gb(256);
    // Q -> out region (scratch until final GEMM overwrites it)
    gemm64_kernel<<<gg, gb, 0, stream>>>(x, Wq, bq, out, 0, 0, nullptr);
    // K -> cache slot 0, V -> cache slot 1 (this IS the new_cache output)
    gemm64_kernel<<<gg, gb, 0, stream>>>(x, Wk, bk, cacheOut, 1, 0, idxp);
    gemm64_kernel<<<gg, gb, 0, stream>>>(x, Wv, bv, cacheOut, 1, 1, idxp);
    // attention: q (out region) x cache -> ctx (ws)
    attn_kernel<<<dim3(4, 128), gb, 0, stream>>>(out, cacheOut, wsctx);
    // output projection: ctx @ Wo -> out region
    gemm64_kernel<<<gg, gb, 0, stream>>>(wsctx, Wo, bo, out, 0, 0, nullptr);
}

// Round 4
// 960.393 us; speedup vs baseline: 2.1259x; 2.1259x over previous
//
#include <hip/hip_runtime.h>
#include <hip/hip_bf16.h>
#include <stdint.h>

// CachedOPTAttention: B=4, T=1024, D=2048, H=32, HD=64, causal, idx=0.
// FP32 buffers; bf16-class error budget (0.10125) -> bf16 MFMA math inside.
// Output: out (8M f32) ++ new_cache (16M f32). idx=0 & update len==max_len ->
// cache fully overwritten; K/V GEMMs write straight into d_out's cache region.
//
// Buffer plan:
//   Q GEMM    : x @ Wq -> d_out[0 : 8M)        (out region, dead until O GEMM)
//   K,V GEMMs : x @ Wk/Wv -> d_out[8M : 24M)   (new_cache region — final output)
//   attention : q (out region) x cache -> ctx in d_ws
//   O GEMM    : ctx @ Wo -> d_out[0 : 8M)

typedef __hip_bfloat16 bf16;
typedef short s16x8 __attribute__((ext_vector_type(8)));
typedef float f32x4 __attribute__((ext_vector_type(4)));

#define T_SEQ   1024
#define D_MODEL 2048

__device__ inline unsigned short f2b(float f) {
    bf16 h = __float2bfloat16(f);
    return *(unsigned short*)&h;
}

// ---------------------------------------------------------------------------
// GEMM: C[4096, 2048] = A[4096, 2048] @ W[2048, 2048] + bias (fp32 in/out,
// bf16 MFMA). 64x64 tile / 256 threads, BK=32. (unchanged from R2 — known good)
// ---------------------------------------------------------------------------
__global__ __launch_bounds__(256)
void gemm64_kernel(const float* __restrict__ A, const float* __restrict__ W,
                   const float* __restrict__ bias, float* __restrict__ out,
                   int mode, int slot, const int* __restrict__ idxp)
{
    __shared__ __align__(16) unsigned short As[64 * 32];
    __shared__ __align__(16) unsigned short Bs[64 * 32];  // W^T tile: Bs[n][k]

    const int tid  = threadIdx.x;
    const int m0   = blockIdx.y * 64;
    const int n0   = blockIdx.x * 64;
    const int wave = tid >> 6;
    const int lane = tid & 63;
    const int quad = lane >> 4;
    const int l15  = lane & 15;

    const int ar = tid >> 2;
    const int ac = (tid & 3) * 8;
    const int wk = tid >> 3;
    const int wc = (tid & 7) * 8;

    f32x4 acc[4];
    #pragma unroll
    for (int t = 0; t < 4; ++t) acc[t] = f32x4{0.f, 0.f, 0.f, 0.f};

    const float4* ag = (const float4*)(A + (size_t)(m0 + ar) * D_MODEL + ac);
    const float4* wg = (const float4*)(W + (size_t)wk * D_MODEL + n0 + wc);

    for (int k0 = 0; k0 < D_MODEL; k0 += 32) {
        float4 a0 = ag[(k0 >> 2) + 0];
        float4 a1 = ag[(k0 >> 2) + 1];
        union { uint4 u; unsigned short s[8]; } ap;
        ap.s[0] = f2b(a0.x); ap.s[1] = f2b(a0.y); ap.s[2] = f2b(a0.z); ap.s[3] = f2b(a0.w);
        ap.s[4] = f2b(a1.x); ap.s[5] = f2b(a1.y); ap.s[6] = f2b(a1.z); ap.s[7] = f2b(a1.w);
        *(uint4*)(As + ar * 32 + ac) = ap.u;

        float4 w0 = wg[((size_t)k0 << 9) + 0];
        float4 w1 = wg[((size_t)k0 << 9) + 1];
        float wv[8] = {w0.x, w0.y, w0.z, w0.w, w1.x, w1.y, w1.z, w1.w};
        #pragma unroll
        for (int j = 0; j < 8; ++j) Bs[(wc + j) * 32 + wk] = f2b(wv[j]);
        __syncthreads();

        s16x8 af = *(const s16x8*)(As + (wave * 16 + l15) * 32 + quad * 8);
        #pragma unroll
        for (int t = 0; t < 4; ++t) {
            s16x8 bfr = *(const s16x8*)(Bs + (t * 16 + l15) * 32 + quad * 8);
            acc[t] = __builtin_amdgcn_mfma_f32_16x16x32_bf16(af, bfr, acc[t], 0, 0, 0);
        }
        __syncthreads();
    }

    const int idx = (mode == 1) ? idxp[0] : 0;
    #pragma unroll
    for (int t = 0; t < 4; ++t) {
        const int col = n0 + t * 16 + l15;
        const float bv = bias[col];
        #pragma unroll
        for (int r = 0; r < 4; ++r) {
            const int m = m0 + wave * 16 + quad * 4 + r;
            const float v = acc[t][r] + bv;
            size_t off;
            if (mode == 0) {
                off = (size_t)m * D_MODEL + col;
            } else {
                const int b  = m >> 10;
                const int tt = ((m & 1023) + idx) & 1023;
                off = ((size_t)(b * 2 + slot) * T_SEQ + tt) * D_MODEL + col;
            }
            out[off] = v;
        }
    }
}

// ---------------------------------------------------------------------------
// MFMA flash attention. Block = 256 thr = 4 waves = one 64-query tile of one
// (b,h). Grid (128, 16): x = b*32+h, y -> qt = 15-y (heaviest tiles first).
// Per 64-key tile: S = Q@K^T via mfma (each wave: 16 queries x 64 keys),
// in-register online softmax (rows owned by lane quads; shfl_xor width-16
// reductions), P -> LDS (C-layout -> A-layout transform), O += P@V^T via mfma.
// O's C-layout row ownership (row=quad*4+r) matches softmax state -> alpha
// rescale is lane-local. All LDS tiles stride 72 (144B = 4 banks mod 32)
// for even bank coverage on frag reads.
// Q scale 0.125 folded into Q staging (exact power of 2).
// ---------------------------------------------------------------------------
#define LDW 72

__global__ __launch_bounds__(256)
void attn_mfma_kernel(const float* __restrict__ q, const float* __restrict__ cache,
                      float* __restrict__ ctx)
{
    __shared__ __align__(16) unsigned short Qs[64 * LDW];  // Qs[q][d]
    __shared__ __align__(16) unsigned short Ks[64 * LDW];  // Ks[key][d]
    __shared__ __align__(16) unsigned short Vt[64 * LDW];  // Vt[d][key]
    __shared__ __align__(16) unsigned short Ps[64 * LDW];  // Ps[q][key]

    const int tid  = threadIdx.x;
    const int wave = tid >> 6;
    const int lane = tid & 63;
    const int quad = lane >> 4;
    const int l15  = lane & 15;

    const int bh = blockIdx.x;          // b*32 + h
    const int b  = bh >> 5;
    const int h  = bh & 31;
    const int qt = 15 - blockIdx.y;     // query tile 0..15

    const int srow = tid >> 2;          // staging row 0..63
    const int part = tid & 3;           // staging 16-dim chunk

    const float* kbase = cache + ((size_t)(b * 2 + 0) * T_SEQ) * D_MODEL + h * 64;
    const float* vbase = cache + ((size_t)(b * 2 + 1) * T_SEQ) * D_MODEL + h * 64;

    // ---- stage Q tile (64q x 64d), scaled by 1/sqrt(64) = 2^-3 (exact) ----
    {
        const float4* qg = (const float4*)(q + (size_t)(b * T_SEQ + qt * 64 + srow) * D_MODEL
                                             + h * 64 + part * 16);
        float4 q0 = qg[0], q1 = qg[1], q2 = qg[2], q3 = qg[3];
        float v[16] = {q0.x, q0.y, q0.z, q0.w, q1.x, q1.y, q1.z, q1.w,
                       q2.x, q2.y, q2.z, q2.w, q3.x, q3.y, q3.z, q3.w};
        union { uint4 u; unsigned short s[8]; } p0, p1;
        #pragma unroll
        for (int i = 0; i < 8; ++i) { p0.s[i] = f2b(v[i] * 0.125f); p1.s[i] = f2b(v[8 + i] * 0.125f); }
        *(uint4*)(Qs + srow * LDW + part * 16)     = p0.u;
        *(uint4*)(Qs + srow * LDW + part * 16 + 8) = p1.u;
    }
    __syncthreads();

    // Q A-frags (hoisted: Qs is never rewritten): A[m=l15][k=quad*8+j (+32)]
    const s16x8 qf0 = *(const s16x8*)(Qs + (wave * 16 + l15) * LDW + quad * 8);
    const s16x8 qf1 = *(const s16x8*)(Qs + (wave * 16 + l15) * LDW + 32 + quad * 8);

    f32x4 oacc[4];
    #pragma unroll
    for (int t = 0; t < 4; ++t) oacc[t] = f32x4{0.f, 0.f, 0.f, 0.f};
    float m_run[4] = {-1e30f, -1e30f, -1e30f, -1e30f};
    float l_run[4] = {0.f, 0.f, 0.f, 0.f};

    for (int kt = 0; kt <= qt; ++kt) {
        __syncthreads();   // prior tile's frag reads done; safe to restage

        // ---- stage K tile (row-major) and V tile (transposed) ----
        {
            const float4* kg = (const float4*)(kbase + (size_t)(kt * 64 + srow) * D_MODEL + part * 16);
            const float4* vg = (const float4*)(vbase + (size_t)(kt * 64 + srow) * D_MODEL + part * 16);
            float4 k0 = kg[0], k1 = kg[1], k2 = kg[2], k3 = kg[3];
            float4 v0 = vg[0], v1 = vg[1], v2 = vg[2], v3 = vg[3];
            float kv[16] = {k0.x, k0.y, k0.z, k0.w, k1.x, k1.y, k1.z, k1.w,
                            k2.x, k2.y, k2.z, k2.w, k3.x, k3.y, k3.z, k3.w};
            float vv[16] = {v0.x, v0.y, v0.z, v0.w, v1.x, v1.y, v1.z, v1.w,
                            v2.x, v2.y, v2.z, v2.w, v3.x, v3.y, v3.z, v3.w};
            union { uint4 u; unsigned short s[8]; } p0, p1;
            #pragma unroll
            for (int i = 0; i < 8; ++i) { p0.s[i] = f2b(kv[i]); p1.s[i] = f2b(kv[8 + i]); }
            *(uint4*)(Ks + srow * LDW + part * 16)     = p0.u;
            *(uint4*)(Ks + srow * LDW + part * 16 + 8) = p1.u;
            #pragma unroll
            for (int j = 0; j < 16; ++j) Vt[(part * 16 + j) * LDW + srow] = f2b(vv[j]);
        }
        __syncthreads();

        // ---- S = Q @ K^T : each wave 16 queries x 64 keys ----
        f32x4 sacc[4];
        #pragma unroll
        for (int t = 0; t < 4; ++t) sacc[t] = f32x4{0.f, 0.f, 0.f, 0.f};
        #pragma unroll
        for (int t = 0; t < 4; ++t) {
            s16x8 kf0 = *(const s16x8*)(Ks + (t * 16 + l15) * LDW + quad * 8);
            s16x8 kf1 = *(const s16x8*)(Ks + (t * 16 + l15) * LDW + 32 + quad * 8);
            sacc[t] = __builtin_amdgcn_mfma_f32_16x16x32_bf16(qf0, kf0, sacc[t], 0, 0, 0);
            sacc[t] = __builtin_amdgcn_mfma_f32_16x16x32_bf16(qf1, kf1, sacc[t], 0, 0, 0);
        }

        // causal mask: only the diagonal tile needs it (same 64-base)
        if (kt == qt) {
            #pragma unroll
            for (int t = 0; t < 4; ++t) {
                const int keyl = t * 16 + l15;
                #pragma unroll
                for (int r = 0; r < 4; ++r) {
                    if (keyl > wave * 16 + quad * 4 + r) sacc[t][r] = -1e30f;
                }
            }
        }

        // ---- online softmax; rows (queries) live in lane quads ----
        float rmax[4];
        #pragma unroll
        for (int r = 0; r < 4; ++r)
            rmax[r] = fmaxf(fmaxf(sacc[0][r], sacc[1][r]), fmaxf(sacc[2][r], sacc[3][r]));
        #pragma unroll
        for (int off = 1; off < 16; off <<= 1) {
            #pragma unroll
            for (int r = 0; r < 4; ++r) rmax[r] = fmaxf(rmax[r], __shfl_xor(rmax[r], off, 16));
        }
        float alpha[4];
        #pragma unroll
        for (int r = 0; r < 4; ++r) {
            const float mnew = fmaxf(m_run[r], rmax[r]);
            alpha[r] = __expf(m_run[r] - mnew);
            m_run[r] = mnew;
        }
        float rsum[4] = {0.f, 0.f, 0.f, 0.f};
        #pragma unroll
        for (int t = 0; t < 4; ++t) {
            #pragma unroll
            for (int r = 0; r < 4; ++r) {
                const float p = __expf(sacc[t][r] - m_run[r]);
                sacc[t][r] = p;
                rsum[r] += p;
            }
        }
        #pragma unroll
        for (int off = 1; off < 16; off <<= 1) {
            #pragma unroll
            for (int r = 0; r < 4; ++r) rsum[r] += __shfl_xor(rsum[r], off, 16);
        }
        #pragma unroll
        for (int r = 0; r < 4; ++r) l_run[r] = l_run[r] * alpha[r] + rsum[r];
        #pragma unroll
        for (int t = 0; t < 4; ++t) {
            #pragma unroll
            for (int r = 0; r < 4; ++r) oacc[t][r] *= alpha[r];
        }

        // ---- P: C-layout regs -> LDS (per-wave private 16-row slab) ----
        #pragma unroll
        for (int t = 0; t < 4; ++t) {
            #pragma unroll
            for (int r = 0; r < 4; ++r)
                Ps[(wave * 16 + quad * 4 + r) * LDW + t * 16 + l15] = f2b(sacc[t][r]);
        }
        // same-wave write->read: compiler orders LDS ops (may-alias) via lgkmcnt

        // ---- O += P @ V^T ----
        s16x8 pf0 = *(const s16x8*)(Ps + (wave * 16 + l15) * LDW + quad * 8);
        s16x8 pf1 = *(const s16x8*)(Ps + (wave * 16 + l15) * LDW + 32 + quad * 8);
        #pragma unroll
        for (int t = 0; t < 4; ++t) {
            s16x8 vf0 = *(const s16x8*)(Vt + (t * 16 + l15) * LDW + quad * 8);
            s16x8 vf1 = *(const s16x8*)(Vt + (t * 16 + l15) * LDW + 32 + quad * 8);
            oacc[t] = __builtin_amdgcn_mfma_f32_16x16x32_bf16(pf0, vf0, oacc[t], 0, 0, 0);
            oacc[t] = __builtin_amdgcn_mfma_f32_16x16x32_bf16(pf1, vf1, oacc[t], 0, 0, 0);
        }
    }

    // ---- epilogue: ctx[b*T + qt*64 + qrow][h*64 + dim] = O / l ----
    float invl[4];
    #pragma unroll
    for (int r = 0; r < 4; ++r) invl[r] = 1.0f / l_run[r];
    #pragma unroll
    for (int r = 0; r < 4; ++r) {
        const int qrow = qt * 64 + wave * 16 + quad * 4 + r;
        float* orow = ctx + (size_t)(b * T_SEQ + qrow) * D_MODEL + h * 64;
        #pragma unroll
        for (int t = 0; t < 4; ++t) orow[t * 16 + l15] = oacc[t][r] * invl[r];
    }
}

// ---------------------------------------------------------------------------
extern "C" void kernel_launch(void* const* d_in, const int* in_sizes, int n_in,
                              void* d_out, int out_size, void* d_ws, size_t ws_size,
                              hipStream_t stream)
{
    const float* x    = (const float*)d_in[0];
    const int*   idxp = (const int*)d_in[3];
    const float* Wq   = (const float*)d_in[4];
    const float* bq   = (const float*)d_in[5];
    const float* Wk   = (const float*)d_in[6];
    const float* bk   = (const float*)d_in[7];
    const float* Wv   = (const float*)d_in[8];
    const float* bv   = (const float*)d_in[9];
    const float* Wo   = (const float*)d_in[10];
    const float* bo   = (const float*)d_in[11];

    float* out      = (float*)d_out;
    float* cacheOut = out + (size_t)4 * T_SEQ * D_MODEL;  // new_cache region
    float* wsctx    = (float*)d_ws;                        // ctx scratch

    const dim3 gg(32, 64), gb(256);
    gemm64_kernel<<<gg, gb, 0, stream>>>(x, Wq, bq, out, 0, 0, nullptr);
    gemm64_kernel<<<gg, gb, 0, stream>>>(x, Wk, bk, cacheOut, 1, 0, idxp);
    gemm64_kernel<<<gg, gb, 0, stream>>>(x, Wv, bv, cacheOut, 1, 1, idxp);
    attn_mfma_kernel<<<dim3(128, 16), gb, 0, stream>>>(out, cacheOut, wsctx);
    gemm64_kernel<<<gg, gb, 0, stream>>>(wsctx, Wo, bo, out, 0, 0, nullptr);
}